// Round 1
// baseline (873.156 us; speedup 1.0000x reference)
//
#include <hip/hip_runtime.h>
#include <hip/hip_bf16.h>

#define NE 16
#define H  2048
#define I  768
#define TK 8
#define NT 4096
#define BM 128
#define BK 64

typedef unsigned short u16;
typedef unsigned int u32;
typedef __attribute__((ext_vector_type(8))) short bf16x8;
typedef __attribute__((ext_vector_type(4))) float f32x4;

__device__ __forceinline__ u16 f2bf(float f) {
    u32 u = __float_as_uint(f);
    u32 r = (u + 0x7fffu + ((u >> 16) & 1u)) >> 16;
    return (u16)r;
}

__device__ __forceinline__ void gload16(const void* g, void* l) {
    __builtin_amdgcn_global_load_lds(
        (const __attribute__((address_space(1))) unsigned int*)g,
        (__attribute__((address_space(3))) unsigned int*)l, 16, 0, 0);
}

// ---------------- routing ----------------
__global__ void route_kernel(const float* __restrict__ rw, const int* __restrict__ ridx,
                             int* __restrict__ cnt, int* __restrict__ tok_cap,
                             float* __restrict__ wt_cap) {
    int t = blockIdx.x * 256 + threadIdx.x;
    if (t >= NT) return;
    int idx[TK];
#pragma unroll
    for (int k = 0; k < TK; k++) idx[k] = ridx[t * TK + k];
#pragma unroll
    for (int e = 0; e < NE; e++) {
        int mult = 0;
#pragma unroll
        for (int k = 0; k < TK; k++) mult += (idx[k] == e) ? 1 : 0;
        if (mult) {
            float w = (float)mult * rw[t * NE + e];
            int slot = atomicAdd(&cnt[e], 1);
            tok_cap[e * NT + slot] = t;
            wt_cap[e * NT + slot] = w;
        }
    }
}

__global__ void prefix_kernel(const int* __restrict__ cnt, int* __restrict__ base) {
    if (threadIdx.x == 0 && blockIdx.x == 0) {
        int s = 0;
        for (int e = 0; e < NE; e++) { base[e] = s; s += cnt[e]; }
        base[NE] = s;
    }
}

__global__ void compact_kernel(const int* __restrict__ cnt, const int* __restrict__ base,
                               const int* __restrict__ tok_cap, const float* __restrict__ wt_cap,
                               int* __restrict__ tok, float* __restrict__ wt) {
    int i = blockIdx.x * 256 + threadIdx.x;
    int e = i >> 12, s = i & 4095;
    if (e < NE && s < cnt[e]) {
        tok[base[e] + s] = tok_cap[e * NT + s];
        wt[base[e] + s]  = wt_cap[e * NT + s];
    }
}

// ---------------- fp32 -> bf16 convert ----------------
__global__ void cvt_hs(const float4* __restrict__ in, uint4* __restrict__ out, int n) {
    int i = blockIdx.x * 256 + threadIdx.x;
    if (i >= n) return;
    float4 a = in[i * 2], b = in[i * 2 + 1];
    uint4 o;
    o.x = (u32)f2bf(a.x) | ((u32)f2bf(a.y) << 16);
    o.y = (u32)f2bf(a.z) | ((u32)f2bf(a.w) << 16);
    o.z = (u32)f2bf(b.x) | ((u32)f2bf(b.y) << 16);
    o.w = (u32)f2bf(b.z) | ((u32)f2bf(b.w) << 16);
    out[i] = o;
}

// transpose + convert: in[e][K][N] f32 -> out[e][N][K] bf16
__global__ void transpose_cvt(const float* __restrict__ in, u16* __restrict__ out,
                              int K, int N) {
    __shared__ float tile[64][65];
    const float* src = in + (size_t)blockIdx.z * K * N;
    u16* dst = out + (size_t)blockIdx.z * (size_t)K * N;
    int n0 = blockIdx.x * 64, k0 = blockIdx.y * 64;
    int tc = threadIdx.x & 63, tr = threadIdx.x >> 6;
    for (int r = tr; r < 64; r += 4)
        tile[r][tc] = src[(size_t)(k0 + r) * N + n0 + tc];
    __syncthreads();
    for (int r = tr; r < 64; r += 4)
        dst[(size_t)(n0 + r) * K + k0 + tc] = f2bf(tile[tc][r]);
}

// ---------------- GEMM1: gathered hs x W1^T, fused SwiGLU ----------------
// block: 128 tokens x 64 inter-cols (gate 64 + up 64 = 128 B-rows). 4 waves,
// each wave = 32 rows x 128 cols (gate/up pairing stays lane-local).
__global__ __launch_bounds__(256, 2) void gemm1_kernel(
    const u16* __restrict__ hsb, const u16* __restrict__ w1t, u16* __restrict__ inter,
    const int* __restrict__ tok, const int* __restrict__ cnt, const int* __restrict__ base) {
    int e = blockIdx.z, mt = blockIdx.y, nt = blockIdx.x;
    int cn = cnt[e];
    if (mt * BM >= cn) return;
    int b0 = base[e];

    __shared__ u16 lA[BM * BK];
    __shared__ u16 lB[BM * BK];

    int tid = threadIdx.x, lane = tid & 63, wv = tid >> 6;

    const u16* gA[4];
    const u16* gB[4];
#pragma unroll
    for (int i = 0; i < 4; i++) {
        int c = i * 256 + tid;
        int r = c >> 3, ko = (c & 7) * 8;
        int rg = mt * BM + r;
        int t = tok[b0 + min(rg, cn - 1)];
        gA[i] = hsb + (size_t)t * H + ko;
        int nrow = (r < 64) ? (nt * 64 + r) : (704 + nt * 64 + r);
        gB[i] = w1t + (size_t)e * 1536 * H + (size_t)nrow * H + ko;
    }
    u16* lAd[4];
    u16* lBd[4];
#pragma unroll
    for (int i = 0; i < 4; i++) {
        lAd[i] = lA + (i * 256 + wv * 64) * 8;
        lBd[i] = lB + (i * 256 + wv * 64) * 8;
    }

    f32x4 acc[2][8];
#pragma unroll
    for (int m = 0; m < 2; m++)
#pragma unroll
        for (int n = 0; n < 8; n++) acc[m][n] = (f32x4)0.0f;

    for (int kt = 0; kt < H / BK; ++kt) {
        __syncthreads();
#pragma unroll
        for (int i = 0; i < 4; i++) { gload16(gA[i], lAd[i]); gload16(gB[i], lBd[i]); }
#pragma unroll
        for (int i = 0; i < 4; i++) { gA[i] += BK; gB[i] += BK; }
        __syncthreads();
#pragma unroll
        for (int s = 0; s < 2; s++) {
            int kk = s * 32 + (lane >> 4) * 8;
            bf16x8 a0 = *(const bf16x8*)&lA[(wv * 32 + (lane & 15)) * BK + kk];
            bf16x8 a1 = *(const bf16x8*)&lA[(wv * 32 + 16 + (lane & 15)) * BK + kk];
#pragma unroll
            for (int n = 0; n < 8; n++) {
                bf16x8 b = *(const bf16x8*)&lB[(n * 16 + (lane & 15)) * BK + kk];
                acc[0][n] = __builtin_amdgcn_mfma_f32_16x16x32_bf16(a0, b, acc[0][n], 0, 0, 0);
                acc[1][n] = __builtin_amdgcn_mfma_f32_16x16x32_bf16(a1, b, acc[1][n], 0, 0, 0);
            }
        }
    }

    int jr = (lane >> 4) * 4, col = lane & 15;
#pragma unroll
    for (int m = 0; m < 2; m++)
#pragma unroll
        for (int j = 0; j < 4; j++) {
            int r = wv * 32 + m * 16 + jr + j;
            int rg = mt * BM + r;
            if (rg < cn) {
                size_t slot = (size_t)(b0 + rg);
#pragma unroll
                for (int n = 0; n < 4; n++) {
                    float g = acc[m][n][j];
                    float u = acc[m][n + 4][j];
                    float sv = g / (1.0f + __expf(-g)) * u;
                    inter[slot * I + nt * 64 + n * 16 + col] = f2bf(sv);
                }
            }
        }
}

// ---------------- GEMM2: inter x W2^T, weighted atomic scatter ----------------
__global__ __launch_bounds__(256, 2) void gemm2_kernel(
    const u16* __restrict__ inter, const u16* __restrict__ w2t, float* __restrict__ out,
    const int* __restrict__ tok, const float* __restrict__ wt,
    const int* __restrict__ cnt, const int* __restrict__ base) {
    int e = blockIdx.z, mt = blockIdx.y, nt = blockIdx.x;
    int cn = cnt[e];
    if (mt * BM >= cn) return;
    int b0 = base[e];

    __shared__ u16 lA[BM * BK];
    __shared__ u16 lB[BM * BK];

    int tid = threadIdx.x, lane = tid & 63, wv = tid >> 6;

    const u16* gA[4];
    const u16* gB[4];
#pragma unroll
    for (int i = 0; i < 4; i++) {
        int c = i * 256 + tid;
        int r = c >> 3, ko = (c & 7) * 8;
        gA[i] = inter + (size_t)(b0 + mt * BM + r) * I + ko;
        gB[i] = w2t + (size_t)e * H * I + (size_t)(nt * BM + r) * I + ko;
    }
    u16* lAd[4];
    u16* lBd[4];
#pragma unroll
    for (int i = 0; i < 4; i++) {
        lAd[i] = lA + (i * 256 + wv * 64) * 8;
        lBd[i] = lB + (i * 256 + wv * 64) * 8;
    }

    f32x4 acc[2][8];
#pragma unroll
    for (int m = 0; m < 2; m++)
#pragma unroll
        for (int n = 0; n < 8; n++) acc[m][n] = (f32x4)0.0f;

    for (int kt = 0; kt < I / BK; ++kt) {
        __syncthreads();
#pragma unroll
        for (int i = 0; i < 4; i++) { gload16(gA[i], lAd[i]); gload16(gB[i], lBd[i]); }
#pragma unroll
        for (int i = 0; i < 4; i++) { gA[i] += BK; gB[i] += BK; }
        __syncthreads();
#pragma unroll
        for (int s = 0; s < 2; s++) {
            int kk = s * 32 + (lane >> 4) * 8;
            bf16x8 a0 = *(const bf16x8*)&lA[(wv * 32 + (lane & 15)) * BK + kk];
            bf16x8 a1 = *(const bf16x8*)&lA[(wv * 32 + 16 + (lane & 15)) * BK + kk];
#pragma unroll
            for (int n = 0; n < 8; n++) {
                bf16x8 b = *(const bf16x8*)&lB[(n * 16 + (lane & 15)) * BK + kk];
                acc[0][n] = __builtin_amdgcn_mfma_f32_16x16x32_bf16(a0, b, acc[0][n], 0, 0, 0);
                acc[1][n] = __builtin_amdgcn_mfma_f32_16x16x32_bf16(a1, b, acc[1][n], 0, 0, 0);
            }
        }
    }

    int jr = (lane >> 4) * 4, col = lane & 15;
#pragma unroll
    for (int m = 0; m < 2; m++)
#pragma unroll
        for (int j = 0; j < 4; j++) {
            int r = wv * 32 + m * 16 + jr + j;
            int rg = mt * BM + r;
            if (rg < cn) {
                int t = tok[b0 + rg];
                float w = wt[b0 + rg];
                float* orow = out + (size_t)t * H + nt * BM;
#pragma unroll
                for (int n = 0; n < 8; n++)
                    atomicAdd(&orow[n * 16 + col], w * acc[m][n][j]);
            }
        }
}

extern "C" void kernel_launch(void* const* d_in, const int* in_sizes, int n_in,
                              void* d_out, int out_size, void* d_ws, size_t ws_size,
                              hipStream_t stream) {
    const float* hs  = (const float*)d_in[0];
    const float* rw  = (const float*)d_in[1];
    const int*   ri  = (const int*)d_in[2];
    const float* w1  = (const float*)d_in[3];
    const float* w2  = (const float*)d_in[4];
    float* out = (float*)d_out;

    char* ws = (char*)d_ws;
    size_t o = 0;
    auto alloc = [&](size_t bytes) { void* p = ws + o; o += (bytes + 255) & ~(size_t)255; return p; };
    u16*   hsb    = (u16*)alloc((size_t)NT * H * 2);
    u16*   w1t    = (u16*)alloc((size_t)NE * 1536 * H * 2);
    u16*   w2t    = (u16*)alloc((size_t)NE * H * I * 2);
    u16*   inter  = (u16*)alloc((size_t)(NT * TK + 256) * I * 2);
    int*   tokcap = (int*)alloc((size_t)NE * NT * 4);
    float* wtcap  = (float*)alloc((size_t)NE * NT * 4);
    int*   tok    = (int*)alloc((size_t)NT * TK * 4);
    float* wt     = (float*)alloc((size_t)NT * TK * 4);
    int*   cnt    = (int*)alloc(64);
    int*   base   = (int*)alloc(128);

    hipMemsetAsync(cnt, 0, 64, stream);
    hipMemsetAsync(out, 0, (size_t)NT * H * 4, stream);

    route_kernel<<<NT / 256, 256, 0, stream>>>(rw, ri, cnt, tokcap, wtcap);
    prefix_kernel<<<1, 64, 0, stream>>>(cnt, base);
    compact_kernel<<<NE * NT / 256, 256, 0, stream>>>(cnt, base, tokcap, wtcap, tok, wt);
    cvt_hs<<<(NT * H / 8 + 255) / 256, 256, 0, stream>>>((const float4*)hs, (uint4*)hsb, NT * H / 8);
    {
        dim3 g(1536 / 64, H / 64, NE);
        transpose_cvt<<<g, 256, 0, stream>>>(w1, w1t, H, 1536);
    }
    {
        dim3 g(H / 64, I / 64, NE);
        transpose_cvt<<<g, 256, 0, stream>>>(w2, w2t, I, H);
    }
    {
        dim3 g(12, 32, NE);
        gemm1_kernel<<<g, 256, 0, stream>>>(hsb, w1t, inter, tok, cnt, base);
    }
    {
        dim3 g(16, 32, NE);
        gemm2_kernel<<<g, 256, 0, stream>>>(inter, w2t, out, tok, wt, cnt, base);
    }
}

// Round 4
// 801.825 us; speedup vs baseline: 1.0890x; 1.0890x over previous
//
#include <hip/hip_runtime.h>
#include <hip/hip_bf16.h>

#define NE 16
#define H  2048
#define I  768
#define TK 8
#define NT 4096
#define BM 128
#define BK 64

typedef unsigned short u16;
typedef unsigned int u32;
typedef __attribute__((ext_vector_type(8))) short bf16x8;
typedef __attribute__((ext_vector_type(4))) float f32x4;

__device__ __forceinline__ u16 f2bf(float f) {
    u32 u = __float_as_uint(f);
    u32 r = (u + 0x7fffu + ((u >> 16) & 1u)) >> 16;
    return (u16)r;
}

__device__ __forceinline__ void gload16(const void* g, void* l) {
    __builtin_amdgcn_global_load_lds(
        (const __attribute__((address_space(1))) unsigned int*)g,
        (__attribute__((address_space(3))) unsigned int*)l, 16, 0, 0);
}

// ---------------- routing ----------------
__global__ void route_kernel(const float* __restrict__ rw, const int* __restrict__ ridx,
                             int* __restrict__ cnt, int* __restrict__ tok_cap,
                             float* __restrict__ wt_cap) {
    int t = blockIdx.x * 256 + threadIdx.x;
    if (t >= NT) return;
    int idx[TK];
#pragma unroll
    for (int k = 0; k < TK; k++) idx[k] = ridx[t * TK + k];
#pragma unroll
    for (int e = 0; e < NE; e++) {
        int mult = 0;
#pragma unroll
        for (int k = 0; k < TK; k++) mult += (idx[k] == e) ? 1 : 0;
        if (mult) {
            float w = (float)mult * rw[t * NE + e];
            int slot = atomicAdd(&cnt[e], 1);
            tok_cap[e * NT + slot] = t;
            wt_cap[e * NT + slot] = w;
        }
    }
}

__global__ void prefix_kernel(const int* __restrict__ cnt, int* __restrict__ base) {
    if (threadIdx.x == 0 && blockIdx.x == 0) {
        int s = 0;
        for (int e = 0; e < NE; e++) { base[e] = s; s += cnt[e]; }
        base[NE] = s;
    }
}

// compaction + inverse (token -> slot list) map for the combine stage
__global__ void compact_kernel(const int* __restrict__ cnt, const int* __restrict__ base,
                               const int* __restrict__ tok_cap, const float* __restrict__ wt_cap,
                               int* __restrict__ tok, float* __restrict__ wt,
                               int* __restrict__ tjc, int* __restrict__ tslot) {
    int i = blockIdx.x * 256 + threadIdx.x;
    int e = i >> 12, s = i & 4095;
    if (e < NE && s < cnt[e]) {
        int t = tok_cap[e * NT + s];
        int slot = base[e] + s;
        tok[slot] = t;
        wt[slot]  = wt_cap[e * NT + s];
        int j = atomicAdd(&tjc[t], 1);
        tslot[t * TK + j] = slot;
    }
}

// ---------------- fp32 -> bf16 convert ----------------
__global__ void cvt_hs(const float4* __restrict__ in, uint4* __restrict__ out, int n) {
    int i = blockIdx.x * 256 + threadIdx.x;
    if (i >= n) return;
    float4 a = in[i * 2], b = in[i * 2 + 1];
    uint4 o;
    o.x = (u32)f2bf(a.x) | ((u32)f2bf(a.y) << 16);
    o.y = (u32)f2bf(a.z) | ((u32)f2bf(a.w) << 16);
    o.z = (u32)f2bf(b.x) | ((u32)f2bf(b.y) << 16);
    o.w = (u32)f2bf(b.z) | ((u32)f2bf(b.w) << 16);
    out[i] = o;
}

// transpose + convert: in[e][K][N] f32 -> out[e][N][K] bf16, u32-packed stores
__global__ void transpose_cvt(const float* __restrict__ in, u32* __restrict__ out,
                              int K, int N) {
    __shared__ float tile[64][65];
    const float* src = in + (size_t)blockIdx.z * K * N;
    u32* dst = out + (size_t)blockIdx.z * (size_t)K * N / 2;
    int n0 = blockIdx.x * 64, k0 = blockIdx.y * 64;
    int tc = threadIdx.x & 63, tr = threadIdx.x >> 6;
    for (int r = tr; r < 64; r += 4)
        tile[r][tc] = src[(size_t)(k0 + r) * N + n0 + tc];
    __syncthreads();
    int kp = threadIdx.x & 31, rr = threadIdx.x >> 5;
    for (int r = rr; r < 64; r += 8) {
        u32 v = (u32)f2bf(tile[kp * 2][r]) | ((u32)f2bf(tile[kp * 2 + 1][r]) << 16);
        dst[(size_t)(n0 + r) * (K / 2) + k0 / 2 + kp] = v;
    }
}

// ---------------- GEMM1: gathered hs x W1^T, fused SwiGLU ----------------
// 1D grid, XCD-chunked swizzle (nwg=6144, %8==0), mt innermost so 32
// consecutive logical blocks on one XCD share a 512KB B panel in L2.
__global__ __launch_bounds__(256, 2) void gemm1_kernel(
    const u16* __restrict__ hsb, const u16* __restrict__ w1t, u16* __restrict__ inter,
    const int* __restrict__ tok, const int* __restrict__ cnt, const int* __restrict__ base) {
    int bid = blockIdx.x;
    int lid = (bid & 7) * (6144 / 8) + (bid >> 3);
    int mt = lid & 31, r2 = lid >> 5;
    int nt = r2 % 12, e = r2 / 12;
    int cn = cnt[e];
    if (mt * BM >= cn) return;
    int b0 = base[e];

    __shared__ u16 lA[BM * BK];
    __shared__ u16 lB[BM * BK];

    int tid = threadIdx.x, lane = tid & 63, wv = tid >> 6;

    const u16* gA[4];
    const u16* gB[4];
#pragma unroll
    for (int i = 0; i < 4; i++) {
        int c = i * 256 + tid;
        int r = c >> 3, ko = (c & 7) * 8;
        int rg = mt * BM + r;
        int t = tok[b0 + min(rg, cn - 1)];
        gA[i] = hsb + (size_t)t * H + ko;
        int nrow = (r < 64) ? (nt * 64 + r) : (704 + nt * 64 + r);
        gB[i] = w1t + (size_t)e * 1536 * H + (size_t)nrow * H + ko;
    }
    u16* lAd[4];
    u16* lBd[4];
#pragma unroll
    for (int i = 0; i < 4; i++) {
        lAd[i] = lA + (i * 256 + wv * 64) * 8;
        lBd[i] = lB + (i * 256 + wv * 64) * 8;
    }

    f32x4 acc[2][8];
#pragma unroll
    for (int m = 0; m < 2; m++)
#pragma unroll
        for (int n = 0; n < 8; n++) acc[m][n] = (f32x4)0.0f;

    for (int kt = 0; kt < H / BK; ++kt) {
        __syncthreads();
#pragma unroll
        for (int i = 0; i < 4; i++) { gload16(gA[i], lAd[i]); gload16(gB[i], lBd[i]); }
#pragma unroll
        for (int i = 0; i < 4; i++) { gA[i] += BK; gB[i] += BK; }
        __syncthreads();
#pragma unroll
        for (int s = 0; s < 2; s++) {
            int kk = s * 32 + (lane >> 4) * 8;
            bf16x8 a0 = *(const bf16x8*)&lA[(wv * 32 + (lane & 15)) * BK + kk];
            bf16x8 a1 = *(const bf16x8*)&lA[(wv * 32 + 16 + (lane & 15)) * BK + kk];
#pragma unroll
            for (int n = 0; n < 8; n++) {
                bf16x8 b = *(const bf16x8*)&lB[(n * 16 + (lane & 15)) * BK + kk];
                acc[0][n] = __builtin_amdgcn_mfma_f32_16x16x32_bf16(a0, b, acc[0][n], 0, 0, 0);
                acc[1][n] = __builtin_amdgcn_mfma_f32_16x16x32_bf16(a1, b, acc[1][n], 0, 0, 0);
            }
        }
    }

    int jr = (lane >> 4) * 4, col = lane & 15;
#pragma unroll
    for (int m = 0; m < 2; m++)
#pragma unroll
        for (int j = 0; j < 4; j++) {
            int r = wv * 32 + m * 16 + jr + j;
            int rg = mt * BM + r;
            if (rg < cn) {
                size_t slot = (size_t)(b0 + rg);
#pragma unroll
                for (int n = 0; n < 4; n++) {
                    float g = acc[m][n][j];
                    float u = acc[m][n + 4][j];
                    float sv = g / (1.0f + __expf(-g)) * u;
                    inter[slot * I + nt * 64 + n * 16 + col] = f2bf(sv);
                }
            }
        }
}

// ---------------- GEMM2: inter x W2^T ----------------
// MODE 0: store bf16 expert rows to eo[slot][H] (no atomics; combine_kernel later)
// MODE 1: weighted fp32 atomicAdd directly into out (workspace-constrained fallback)
// 1D grid, XCD-chunked swizzle (nwg=8192, %8==0), mt innermost.
template <int MODE>
__global__ __launch_bounds__(256, 2) void gemm2_kernel(
    const u16* __restrict__ inter, const u16* __restrict__ w2t,
    u16* __restrict__ eo, float* __restrict__ out,
    const int* __restrict__ tok, const float* __restrict__ wt,
    const int* __restrict__ cnt, const int* __restrict__ base) {
    int bid = blockIdx.x;
    int lid = (bid & 7) * (8192 / 8) + (bid >> 3);
    int mt = lid & 31, r2 = lid >> 5;
    int nt = r2 & 15, e = r2 >> 4;
    int cn = cnt[e];
    if (mt * BM >= cn) return;
    int b0 = base[e];

    __shared__ u16 lA[BM * BK];
    __shared__ u16 lB[BM * BK];

    int tid = threadIdx.x, lane = tid & 63, wv = tid >> 6;

    const u16* gA[4];
    const u16* gB[4];
#pragma unroll
    for (int i = 0; i < 4; i++) {
        int c = i * 256 + tid;
        int r = c >> 3, ko = (c & 7) * 8;
        gA[i] = inter + (size_t)(b0 + mt * BM + r) * I + ko;
        gB[i] = w2t + (size_t)e * H * I + (size_t)(nt * BM + r) * I + ko;
    }
    u16* lAd[4];
    u16* lBd[4];
#pragma unroll
    for (int i = 0; i < 4; i++) {
        lAd[i] = lA + (i * 256 + wv * 64) * 8;
        lBd[i] = lB + (i * 256 + wv * 64) * 8;
    }

    f32x4 acc[2][8];
#pragma unroll
    for (int m = 0; m < 2; m++)
#pragma unroll
        for (int n = 0; n < 8; n++) acc[m][n] = (f32x4)0.0f;

    for (int kt = 0; kt < I / BK; ++kt) {
        __syncthreads();
#pragma unroll
        for (int i = 0; i < 4; i++) { gload16(gA[i], lAd[i]); gload16(gB[i], lBd[i]); }
#pragma unroll
        for (int i = 0; i < 4; i++) { gA[i] += BK; gB[i] += BK; }
        __syncthreads();
#pragma unroll
        for (int s = 0; s < 2; s++) {
            int kk = s * 32 + (lane >> 4) * 8;
            bf16x8 a0 = *(const bf16x8*)&lA[(wv * 32 + (lane & 15)) * BK + kk];
            bf16x8 a1 = *(const bf16x8*)&lA[(wv * 32 + 16 + (lane & 15)) * BK + kk];
#pragma unroll
            for (int n = 0; n < 8; n++) {
                bf16x8 b = *(const bf16x8*)&lB[(n * 16 + (lane & 15)) * BK + kk];
                acc[0][n] = __builtin_amdgcn_mfma_f32_16x16x32_bf16(a0, b, acc[0][n], 0, 0, 0);
                acc[1][n] = __builtin_amdgcn_mfma_f32_16x16x32_bf16(a1, b, acc[1][n], 0, 0, 0);
            }
        }
    }

    int jr = (lane >> 4) * 4, col = lane & 15;
#pragma unroll
    for (int m = 0; m < 2; m++)
#pragma unroll
        for (int j = 0; j < 4; j++) {
            int r = wv * 32 + m * 16 + jr + j;
            int rg = mt * BM + r;
            if (rg < cn) {
                if (MODE == 0) {
                    u16* row = eo + (size_t)(b0 + rg) * H + nt * BM;
#pragma unroll
                    for (int n = 0; n < 8; n++)
                        row[n * 16 + col] = f2bf(acc[m][n][j]);
                } else {
                    int t = tok[b0 + rg];
                    float w = wt[b0 + rg];
                    float* orow = out + (size_t)t * H + nt * BM;
#pragma unroll
                    for (int n = 0; n < 8; n++)
                        atomicAdd(&orow[n * 16 + col], w * acc[m][n][j]);
                }
            }
        }
}

// ---------------- combine: out[t] = sum_j wt[slot_j] * eo[slot_j] ----------------
__global__ __launch_bounds__(256) void combine_kernel(
    const u16* __restrict__ eo, const float* __restrict__ wt,
    const int* __restrict__ tjc, const int* __restrict__ tslot,
    float* __restrict__ out) {
    int t = blockIdx.x;
    int c = threadIdx.x * 8;
    float acc[8];
#pragma unroll
    for (int i = 0; i < 8; i++) acc[i] = 0.0f;
    int jc = tjc[t];
    for (int j = 0; j < jc; j++) {
        int slot = tslot[t * TK + j];
        float w = wt[slot];
        uint4 v = *(const uint4*)(eo + (size_t)slot * H + c);
        acc[0] += w * __uint_as_float(v.x << 16);
        acc[1] += w * __uint_as_float(v.x & 0xffff0000u);
        acc[2] += w * __uint_as_float(v.y << 16);
        acc[3] += w * __uint_as_float(v.y & 0xffff0000u);
        acc[4] += w * __uint_as_float(v.z << 16);
        acc[5] += w * __uint_as_float(v.z & 0xffff0000u);
        acc[6] += w * __uint_as_float(v.w << 16);
        acc[7] += w * __uint_as_float(v.w & 0xffff0000u);
    }
    float4* o = (float4*)(out + (size_t)t * H + c);
    o[0] = make_float4(acc[0], acc[1], acc[2], acc[3]);
    o[1] = make_float4(acc[4], acc[5], acc[6], acc[7]);
}

extern "C" void kernel_launch(void* const* d_in, const int* in_sizes, int n_in,
                              void* d_out, int out_size, void* d_ws, size_t ws_size,
                              hipStream_t stream) {
    const float* hs  = (const float*)d_in[0];
    const float* rw  = (const float*)d_in[1];
    const int*   ri  = (const int*)d_in[2];
    const float* w1  = (const float*)d_in[3];
    const float* w2  = (const float*)d_in[4];
    float* out = (float*)d_out;

    char* ws = (char*)d_ws;
    size_t o = 0;
    auto alloc = [&](size_t bytes) { void* p = ws + o; o += (bytes + 255) & ~(size_t)255; return p; };
    // small buffers first, eo last so the fallback path needs none of its space
    int*   tokcap = (int*)alloc((size_t)NE * NT * 4);
    float* wtcap  = (float*)alloc((size_t)NE * NT * 4);
    int*   tok    = (int*)alloc((size_t)NT * TK * 4);
    float* wt     = (float*)alloc((size_t)NT * TK * 4);
    int*   tjc    = (int*)alloc((size_t)NT * 4);
    int*   tslot  = (int*)alloc((size_t)NT * TK * 4);
    int*   cnt    = (int*)alloc(64);
    int*   base   = (int*)alloc(128);
    u16*   hsb    = (u16*)alloc((size_t)NT * H * 2);
    u16*   w1t    = (u16*)alloc((size_t)NE * 1536 * H * 2);
    u16*   w2t    = (u16*)alloc((size_t)NE * H * I * 2);
    u16*   inter  = (u16*)alloc((size_t)(NT * TK + 256) * I * 2);
    u16*   eo     = (u16*)alloc((size_t)(NT * TK + 256) * H * 2);
    // eo-path only if workspace accommodates it (ws_size constant -> same work every call)
    const bool use_eo = (o <= ws_size);

    hipMemsetAsync(cnt, 0, 64, stream);
    hipMemsetAsync(tjc, 0, (size_t)NT * 4, stream);
    if (!use_eo)
        hipMemsetAsync(out, 0, (size_t)NT * H * 4, stream);

    route_kernel<<<NT / 256, 256, 0, stream>>>(rw, ri, cnt, tokcap, wtcap);
    prefix_kernel<<<1, 64, 0, stream>>>(cnt, base);
    compact_kernel<<<NE * NT / 256, 256, 0, stream>>>(cnt, base, tokcap, wtcap, tok, wt, tjc, tslot);
    cvt_hs<<<(NT * H / 8 + 255) / 256, 256, 0, stream>>>((const float4*)hs, (uint4*)hsb, NT * H / 8);
    {
        dim3 g(1536 / 64, H / 64, NE);
        transpose_cvt<<<g, 256, 0, stream>>>(w1, (u32*)w1t, H, 1536);
    }
    {
        dim3 g(H / 64, I / 64, NE);
        transpose_cvt<<<g, 256, 0, stream>>>(w2, (u32*)w2t, I, H);
    }
    gemm1_kernel<<<6144, 256, 0, stream>>>(hsb, w1t, inter, tok, cnt, base);
    if (use_eo) {
        gemm2_kernel<0><<<8192, 256, 0, stream>>>(inter, w2t, eo, out, tok, wt, cnt, base);
        combine_kernel<<<NT, 256, 0, stream>>>(eo, wt, tjc, tslot, out);
    } else {
        gemm2_kernel<1><<<8192, 256, 0, stream>>>(inter, w2t, eo, out, tok, wt, cnt, base);
    }
}

// Round 7
// 713.572 us; speedup vs baseline: 1.2236x; 1.1237x over previous
//
#include <hip/hip_runtime.h>
#include <hip/hip_bf16.h>

#define NE 16
#define H  2048
#define I  768
#define TK 8
#define NT 4096

typedef unsigned short u16;
typedef unsigned int u32;
typedef __attribute__((ext_vector_type(8))) short bf16x8;
typedef __attribute__((ext_vector_type(4))) float f32x4;

__device__ __forceinline__ u16 f2bf(float f) {
    u32 u = __float_as_uint(f);
    u32 r = (u + 0x7fffu + ((u >> 16) & 1u)) >> 16;
    return (u16)r;
}

__device__ __forceinline__ void gload16(const void* g, void* l) {
    __builtin_amdgcn_global_load_lds(
        (const __attribute__((address_space(1))) unsigned int*)g,
        (__attribute__((address_space(3))) unsigned int*)l, 16, 0, 0);
}

// ---- 8-phase template plumbing ----
__device__ __forceinline__ void BAR() {
    __builtin_amdgcn_sched_barrier(0);
    __builtin_amdgcn_s_barrier();
    __builtin_amdgcn_sched_barrier(0);
}
__device__ __forceinline__ void WLDS() {
    asm volatile("s_waitcnt lgkmcnt(0)" ::: "memory");
    __builtin_amdgcn_sched_barrier(0);
}
#define VM4() asm volatile("s_waitcnt vmcnt(4)" ::: "memory")

#define MF(a, b, c) __builtin_amdgcn_mfma_f32_16x16x32_bf16(a, b, c, 0, 0, 0)

// swizzled frag read: logical k-slot q, stored slot q ^ ((row>>1)&3)
#define FRAG(REG, ROW) (*(const bf16x8*)((REG) + (ROW)*32 + ((q ^ ((((ROW) >> 1)) & 3)) * 8)))

// stage one 256x32 K-half: 2 x global_load_lds(16B) per thread, linear LDS dest
#define STG(PR0, PR1, DST, KO)                       \
    do {                                             \
        gload16((PR0) + (KO), (DST) + tid * 8);      \
        gload16((PR1) + (KO), (DST) + 4096 + tid * 8); \
    } while (0)

#define MFMA_Q(MH)                                                                     \
    do {                                                                               \
        acc[(MH)*4+0][0]=MF(af0,bf0,acc[(MH)*4+0][0]); acc[(MH)*4+0][1]=MF(af0,bf1,acc[(MH)*4+0][1]); \
        acc[(MH)*4+0][2]=MF(af0,bf2,acc[(MH)*4+0][2]); acc[(MH)*4+0][3]=MF(af0,bf3,acc[(MH)*4+0][3]); \
        acc[(MH)*4+1][0]=MF(af1,bf0,acc[(MH)*4+1][0]); acc[(MH)*4+1][1]=MF(af1,bf1,acc[(MH)*4+1][1]); \
        acc[(MH)*4+1][2]=MF(af1,bf2,acc[(MH)*4+1][2]); acc[(MH)*4+1][3]=MF(af1,bf3,acc[(MH)*4+1][3]); \
        acc[(MH)*4+2][0]=MF(af2,bf0,acc[(MH)*4+2][0]); acc[(MH)*4+2][1]=MF(af2,bf1,acc[(MH)*4+2][1]); \
        acc[(MH)*4+2][2]=MF(af2,bf2,acc[(MH)*4+2][2]); acc[(MH)*4+2][3]=MF(af2,bf3,acc[(MH)*4+2][3]); \
        acc[(MH)*4+3][0]=MF(af3,bf0,acc[(MH)*4+3][0]); acc[(MH)*4+3][1]=MF(af3,bf1,acc[(MH)*4+3][1]); \
        acc[(MH)*4+3][2]=MF(af3,bf2,acc[(MH)*4+3][2]); acc[(MH)*4+3][3]=MF(af3,bf3,acc[(MH)*4+3][3]); \
    } while (0)

// one K-tile = 4 phases. Stage schedule (dead-at-issue verified):
//  p1 -> other-buf A ks1 (tile T1), p2 -> other-buf B ks1 (T1),
//  p3 -> own-buf A ks0 (tile T2),  p4 -> own-buf B ks0 (T2) + vmcnt(4)
#define KTILE(cA0, cA1, cB0, cB1, oA1, oB1, T1, T2)                           \
    do {                                                                      \
        af0 = FRAG(cA0, wm*128 +  0 + ln); af1 = FRAG(cA0, wm*128 + 16 + ln); \
        af2 = FRAG(cA0, wm*128 + 32 + ln); af3 = FRAG(cA0, wm*128 + 48 + ln); \
        bf0 = FRAG(cB0, wn*64 +  0 + ln);  bf1 = FRAG(cB0, wn*64 + 16 + ln);  \
        bf2 = FRAG(cB0, wn*64 + 32 + ln);  bf3 = FRAG(cB0, wn*64 + 48 + ln);  \
        STG(pA0, pA1, oA1, (T1)*64 + 32);                                     \
        BAR(); WLDS();                                                        \
        __builtin_amdgcn_s_setprio(1); MFMA_Q(0); __builtin_amdgcn_s_setprio(0); \
        BAR();                                                                \
        af0 = FRAG(cA0, wm*128 + 64 + ln); af1 = FRAG(cA0, wm*128 + 80 + ln); \
        af2 = FRAG(cA0, wm*128 + 96 + ln); af3 = FRAG(cA0, wm*128 +112 + ln); \
        STG(pB0, pB1, oB1, (T1)*64 + 32);                                     \
        BAR(); WLDS();                                                        \
        __builtin_amdgcn_s_setprio(1); MFMA_Q(1); __builtin_amdgcn_s_setprio(0); \
        BAR();                                                                \
        af0 = FRAG(cA1, wm*128 +  0 + ln); af1 = FRAG(cA1, wm*128 + 16 + ln); \
        af2 = FRAG(cA1, wm*128 + 32 + ln); af3 = FRAG(cA1, wm*128 + 48 + ln); \
        bf0 = FRAG(cB1, wn*64 +  0 + ln);  bf1 = FRAG(cB1, wn*64 + 16 + ln);  \
        bf2 = FRAG(cB1, wn*64 + 32 + ln);  bf3 = FRAG(cB1, wn*64 + 48 + ln);  \
        STG(pA0, pA1, cA0, (T2)*64);                                          \
        BAR(); WLDS();                                                        \
        __builtin_amdgcn_s_setprio(1); MFMA_Q(0); __builtin_amdgcn_s_setprio(0); \
        BAR();                                                                \
        af0 = FRAG(cA1, wm*128 + 64 + ln); af1 = FRAG(cA1, wm*128 + 80 + ln); \
        af2 = FRAG(cA1, wm*128 + 96 + ln); af3 = FRAG(cA1, wm*128 +112 + ln); \
        STG(pB0, pB1, cB0, (T2)*64);                                          \
        VM4();                                                                \
        BAR(); WLDS();                                                        \
        __builtin_amdgcn_s_setprio(1); MFMA_Q(1); __builtin_amdgcn_s_setprio(0); \
        BAR();                                                                \
    } while (0)

#define GEMM_PRO_AND_DECLS()                                                  \
    u16* const sA00 = sm;         u16* const sA01 = sm + 8192;                \
    u16* const sA10 = sm + 16384; u16* const sA11 = sm + 24576;               \
    u16* const sB00 = sm + 32768; u16* const sB01 = sm + 40960;               \
    u16* const sB10 = sm + 49152; u16* const sB11 = sm + 57344;               \
    f32x4 acc[8][4];                                                          \
    _Pragma("unroll") for (int _i = 0; _i < 8; _i++)                          \
    _Pragma("unroll") for (int _j = 0; _j < 4; _j++) acc[_i][_j] = (f32x4)0.0f; \
    bf16x8 af0, af1, af2, af3, bf0, bf1, bf2, bf3;                            \
    /* prologue: halves for tile0 (all 4) + tile1 ks0 (A,B), then vmcnt(4) */ \
    STG(pA0, pA1, sA00, 0);  STG(pB0, pB1, sB00, 0);                          \
    STG(pA0, pA1, sA01, 32); STG(pB0, pB1, sB01, 32);                         \
    STG(pA0, pA1, sA10, 64); STG(pB0, pB1, sB10, 64);                         \
    VM4(); BAR();

// ---------------- routing ----------------
__global__ void route_kernel(const float* __restrict__ rw, const int* __restrict__ ridx,
                             int* __restrict__ cnt, int* __restrict__ tok_cap,
                             float* __restrict__ wt_cap) {
    int t = blockIdx.x * 256 + threadIdx.x;
    if (t >= NT) return;
    int idx[TK];
#pragma unroll
    for (int k = 0; k < TK; k++) idx[k] = ridx[t * TK + k];
#pragma unroll
    for (int e = 0; e < NE; e++) {
        int mult = 0;
#pragma unroll
        for (int k = 0; k < TK; k++) mult += (idx[k] == e) ? 1 : 0;
        if (mult) {
            float w = (float)mult * rw[t * NE + e];
            int slot = atomicAdd(&cnt[e], 1);
            tok_cap[e * NT + slot] = t;
            wt_cap[e * NT + slot] = w;
        }
    }
}

__global__ void prefix_kernel(const int* __restrict__ cnt, int* __restrict__ base) {
    if (threadIdx.x == 0 && blockIdx.x == 0) {
        int s = 0;
        for (int e = 0; e < NE; e++) { base[e] = s; s += cnt[e]; }
        base[NE] = s;
    }
}

__global__ void compact_kernel(const int* __restrict__ cnt, const int* __restrict__ base,
                               const int* __restrict__ tok_cap, const float* __restrict__ wt_cap,
                               int* __restrict__ tok, float* __restrict__ wt,
                               int* __restrict__ tjc, int* __restrict__ tslot) {
    int i = blockIdx.x * 256 + threadIdx.x;
    int e = i >> 12, s = i & 4095;
    if (e < NE && s < cnt[e]) {
        int t = tok_cap[e * NT + s];
        int slot = base[e] + s;
        tok[slot] = t;
        wt[slot]  = wt_cap[e * NT + s];
        int j = atomicAdd(&tjc[t], 1);
        tslot[t * TK + j] = slot;
    }
}

// ---------------- fp32 -> bf16 convert ----------------
__global__ void cvt_hs(const float4* __restrict__ in, uint4* __restrict__ out, int n) {
    int i = blockIdx.x * 256 + threadIdx.x;
    if (i >= n) return;
    float4 a = in[i * 2], b = in[i * 2 + 1];
    uint4 o;
    o.x = (u32)f2bf(a.x) | ((u32)f2bf(a.y) << 16);
    o.y = (u32)f2bf(a.z) | ((u32)f2bf(a.w) << 16);
    o.z = (u32)f2bf(b.x) | ((u32)f2bf(b.y) << 16);
    o.w = (u32)f2bf(b.z) | ((u32)f2bf(b.w) << 16);
    out[i] = o;
}

// transpose + convert: in[e][K][N] f32 -> out[e][N][K] bf16, u32-packed stores
__global__ void transpose_cvt(const float* __restrict__ in, u32* __restrict__ out,
                              int K, int N) {
    __shared__ float tile[64][65];
    const float* src = in + (size_t)blockIdx.z * K * N;
    u32* dst = out + (size_t)blockIdx.z * (size_t)K * N / 2;
    int n0 = blockIdx.x * 64, k0 = blockIdx.y * 64;
    int tc = threadIdx.x & 63, tr = threadIdx.x >> 6;
    for (int r = tr; r < 64; r += 4)
        tile[r][tc] = src[(size_t)(k0 + r) * N + n0 + tc];
    __syncthreads();
    int kp = threadIdx.x & 31, rr = threadIdx.x >> 5;
    for (int r = rr; r < 64; r += 8) {
        u32 v = (u32)f2bf(tile[kp * 2][r]) | ((u32)f2bf(tile[kp * 2 + 1][r]) << 16);
        dst[(size_t)(n0 + r) * (K / 2) + k0 / 2 + kp] = v;
    }
}

// ---------------- GEMM1 (8-phase 256x256): gathered hs x W1^T, fused SwiGLU ----------------
// B-tile rows interleave gate/up at 16-col granularity: b = 32g + 16u + r
// -> global W1t row = 768u + nt*128 + g*16 + r. SwiGLU pairing lane-local.
__global__ __launch_bounds__(512, 2) void gemm1_kernel(
    const u16* __restrict__ hsb, const u16* __restrict__ w1t, u16* __restrict__ inter,
    const int* __restrict__ tok, const int* __restrict__ cnt, const int* __restrict__ base) {
    __shared__ u16 sm[65536];
    int bid = blockIdx.x;
    int lid = (bid & 7) * (1536 / 8) + (bid >> 3);
    int mt = lid & 15;
    int r2 = lid >> 4;
    int nt = r2 % 6, e = r2 / 6;
    int cn = cnt[e];
    if (mt * 256 >= cn) return;
    int b0 = base[e];

    int tid = threadIdx.x;
    int lane = tid & 63, wid = tid >> 6;
    int wm = wid >> 2, wn = wid & 3;
    int ln = lane & 15, q = lane >> 4;

    // staging constants: thread owns rows r0 (round 0) and r0+128 (round 1), k-slot sl
    int r0 = tid >> 2;
    int sl = (tid & 3) ^ ((r0 >> 1) & 3);
    int ta = b0 + min(mt * 256 + r0, cn - 1);
    int tb = b0 + min(mt * 256 + r0 + 128, cn - 1);
    const u16* pA0 = hsb + (size_t)tok[ta] * H + sl * 8;
    const u16* pA1 = hsb + (size_t)tok[tb] * H + sl * 8;
    int g0 = r0 >> 5, u0 = (r0 >> 4) & 1, rr0 = r0 & 15;
    int b1r = r0 + 128;
    int g1 = b1r >> 5, u1 = (b1r >> 4) & 1, rr1 = b1r & 15;
    const u16* pB0 = w1t + (size_t)e * 1536 * H + (size_t)(768 * u0 + nt * 128 + g0 * 16 + rr0) * H + sl * 8;
    const u16* pB1 = w1t + (size_t)e * 1536 * H + (size_t)(768 * u1 + nt * 128 + g1 * 16 + rr1) * H + sl * 8;

    GEMM_PRO_AND_DECLS();

    for (int t = 0; t < 32; t += 2) {
        int u2 = t + 2; if (u2 >= 32) u2 -= 32;
        int u3 = t + 3; if (u3 >= 32) u3 -= 32;
        KTILE(sA00, sA01, sB00, sB01, sA11, sB11, t + 1, u2);
        KTILE(sA10, sA11, sB10, sB11, sA01, sB01, u2, u3);
    }

    // epilogue: SwiGLU, write inter[slot][I]
    int jr = q * 4;
#pragma unroll
    for (int mf = 0; mf < 8; mf++) {
#pragma unroll
        for (int j = 0; j < 4; j++) {
            int rg = mt * 256 + wm * 128 + mf * 16 + jr + j;
            if (rg < cn) {
                size_t slot = (size_t)(b0 + rg);
#pragma unroll
                for (int p = 0; p < 2; p++) {
                    float gg = acc[mf][2 * p][j];
                    float uu = acc[mf][2 * p + 1][j];
                    float sv = gg / (1.0f + __expf(-gg)) * uu;
                    inter[slot * I + nt * 128 + (2 * wn + p) * 16 + ln] = f2bf(sv);
                }
            }
        }
    }
}

// ---------------- GEMM2 (8-phase 256x256): inter x W2^T -> eo[slot][H] bf16 ----------------
__global__ __launch_bounds__(512, 2) void gemm2_kernel(
    const u16* __restrict__ inter, const u16* __restrict__ w2t, u16* __restrict__ eo,
    const int* __restrict__ cnt, const int* __restrict__ base) {
    __shared__ u16 sm[65536];
    int bid = blockIdx.x;
    int lid = (bid & 7) * (2048 / 8) + (bid >> 3);
    int mt = lid & 15;
    int r2 = lid >> 4;
    int nt = r2 & 7, e = r2 >> 3;
    int cn = cnt[e];
    if (mt * 256 >= cn) return;
    int b0 = base[e];

    int tid = threadIdx.x;
    int lane = tid & 63, wid = tid >> 6;
    int wm = wid >> 2, wn = wid & 3;
    int ln = lane & 15, q = lane >> 4;

    int r0 = tid >> 2;
    int sl = (tid & 3) ^ ((r0 >> 1) & 3);
    const u16* pA0 = inter + (size_t)(b0 + mt * 256 + r0) * I + sl * 8;
    const u16* pA1 = inter + (size_t)(b0 + mt * 256 + r0 + 128) * I + sl * 8;
    const u16* pB0 = w2t + (size_t)e * H * I + (size_t)(nt * 256 + r0) * I + sl * 8;
    const u16* pB1 = w2t + (size_t)e * H * I + (size_t)(nt * 256 + r0 + 128) * I + sl * 8;

    GEMM_PRO_AND_DECLS();

    for (int t = 0; t < 12; t += 2) {
        int u2 = t + 2; if (u2 >= 12) u2 -= 12;
        int u3 = t + 3; if (u3 >= 12) u3 -= 12;
        KTILE(sA00, sA01, sB00, sB01, sA11, sB11, t + 1, u2);
        KTILE(sA10, sA11, sB10, sB11, sA01, sB01, u2, u3);
    }

    int jr = q * 4;
#pragma unroll
    for (int mf = 0; mf < 8; mf++) {
#pragma unroll
        for (int j = 0; j < 4; j++) {
            int rg = mt * 256 + wm * 128 + mf * 16 + jr + j;
            if (rg < cn) {
                u16* row = eo + (size_t)(b0 + rg) * H + nt * 256 + wn * 64;
#pragma unroll
                for (int n = 0; n < 4; n++)
                    row[n * 16 + ln] = f2bf(acc[mf][n][j]);
            }
        }
    }
}

// ---------------- combine: out[t] = sum_j wt[slot_j] * eo[slot_j] ----------------
__global__ __launch_bounds__(256) void combine_kernel(
    const u16* __restrict__ eo, const float* __restrict__ wt,
    const int* __restrict__ tjc, const int* __restrict__ tslot,
    float* __restrict__ out) {
    int t = blockIdx.x;
    int c = threadIdx.x * 8;
    float acc[8];
#pragma unroll
    for (int i = 0; i < 8; i++) acc[i] = 0.0f;
    int jc = tjc[t];
    for (int j = 0; j < jc; j++) {
        int slot = tslot[t * TK + j];
        float w = wt[slot];
        uint4 v = *(const uint4*)(eo + (size_t)slot * H + c);
        acc[0] += w * __uint_as_float(v.x << 16);
        acc[1] += w * __uint_as_float(v.x & 0xffff0000u);
        acc[2] += w * __uint_as_float(v.y << 16);
        acc[3] += w * __uint_as_float(v.y & 0xffff0000u);
        acc[4] += w * __uint_as_float(v.z << 16);
        acc[5] += w * __uint_as_float(v.z & 0xffff0000u);
        acc[6] += w * __uint_as_float(v.w << 16);
        acc[7] += w * __uint_as_float(v.w & 0xffff0000u);
    }
    float4* o = (float4*)(out + (size_t)t * H + c);
    o[0] = make_float4(acc[0], acc[1], acc[2], acc[3]);
    o[1] = make_float4(acc[4], acc[5], acc[6], acc[7]);
}

extern "C" void kernel_launch(void* const* d_in, const int* in_sizes, int n_in,
                              void* d_out, int out_size, void* d_ws, size_t ws_size,
                              hipStream_t stream) {
    const float* hs  = (const float*)d_in[0];
    const float* rw  = (const float*)d_in[1];
    const int*   ri  = (const int*)d_in[2];
    const float* w1  = (const float*)d_in[3];
    const float* w2  = (const float*)d_in[4];
    float* out = (float*)d_out;

    char* ws = (char*)d_ws;
    size_t o = 0;
    auto alloc = [&](size_t bytes) { void* p = ws + o; o += (bytes + 255) & ~(size_t)255; return p; };
    int*   tokcap = (int*)alloc((size_t)NE * NT * 4);
    float* wtcap  = (float*)alloc((size_t)NE * NT * 4);
    int*   tok    = (int*)alloc((size_t)NT * TK * 4);
    float* wt     = (float*)alloc((size_t)NT * TK * 4);
    int*   tjc    = (int*)alloc((size_t)NT * 4);
    int*   tslot  = (int*)alloc((size_t)NT * TK * 4);
    int*   cnt    = (int*)alloc(64);
    int*   base   = (int*)alloc(128);
    u16*   hsb    = (u16*)alloc((size_t)NT * H * 2);
    u16*   w1t    = (u16*)alloc((size_t)NE * 1536 * H * 2);
    u16*   w2t    = (u16*)alloc((size_t)NE * H * I * 2);
    u16*   inter  = (u16*)alloc((size_t)(NT * TK + 256) * I * 2);
    u16*   eo     = (u16*)alloc((size_t)(NT * TK + 256) * H * 2);
    (void)ws_size;

    hipMemsetAsync(cnt, 0, 64, stream);
    hipMemsetAsync(tjc, 0, (size_t)NT * 4, stream);

    route_kernel<<<NT / 256, 256, 0, stream>>>(rw, ri, cnt, tokcap, wtcap);
    prefix_kernel<<<1, 64, 0, stream>>>(cnt, base);
    compact_kernel<<<NE * NT / 256, 256, 0, stream>>>(cnt, base, tokcap, wtcap, tok, wt, tjc, tslot);
    cvt_hs<<<(NT * H / 8 + 255) / 256, 256, 0, stream>>>((const float4*)hs, (uint4*)hsb, NT * H / 8);
    {
        dim3 g(1536 / 64, H / 64, NE);
        transpose_cvt<<<g, 256, 0, stream>>>(w1, (u32*)w1t, H, 1536);
    }
    {
        dim3 g(H / 64, I / 64, NE);
        transpose_cvt<<<g, 256, 0, stream>>>(w2, (u32*)w2t, I, H);
    }
    gemm1_kernel<<<1536, 512, 0, stream>>>(hsb, w1t, inter, tok, cnt, base);
    gemm2_kernel<<<2048, 512, 0, stream>>>(inter, w2t, eo, cnt, base);
    combine_kernel<<<NT, 256, 0, stream>>>(eo, wt, tjc, tslot, out);
}